// Round 5
// baseline (278.788 us; speedup 1.0000x reference)
//
#include <hip/hip_runtime.h>

#define S_DIM 128
#define I_DIM 384
#define IN_DIM 256
#define PD 32
#define ODIM 128

typedef __attribute__((ext_vector_type(8))) __bf16 bf16x8;
typedef __attribute__((ext_vector_type(4))) float f32x4;

#define MFMA16(a, b, c) __builtin_amdgcn_mfma_f32_16x16x32_bf16((a), (b), (c), 0, 0, 0)

__device__ inline unsigned short f2bf(float f) {
    unsigned int u = __builtin_bit_cast(unsigned int, f);
    unsigned int r = (u + 0x7FFFu + ((u >> 16) & 1u)) >> 16;
    return (unsigned short)r;
}

// ---------------- prep: cast/transpose weights to bf16 ----------------
// W2s is SLICE-MAJOR: W2s[e][f][d]  (32 x 128 x 32): one k-slice (e) of all
// 128 f-rows is 8 KB contiguous; a wave's 16 f-rows are 1 KB contiguous.
__global__ void prep_cast(const float* __restrict__ Wp, const float* __restrict__ W2,
                          unsigned short* __restrict__ WpT, unsigned short* __restrict__ W2s) {
    int t = blockIdx.x * 256 + threadIdx.x;
    if (t < 64 * 256) {
        int f = t >> 8, k = t & 255;
        WpT[t] = f2bf(Wp[k * 64 + f]);
    }
    if (t < 128 * 1024) {
        int e = t >> 12;
        int f = (t >> 5) & 127;
        int d = t & 31;
        W2s[t] = f2bf(W2[(d * 32 + e) * 128 + f]);
    }
}

// ---------------- norm: gram of mask -> store INVERSE ----------------
__global__ void norm_kernel(const float* __restrict__ mask, float* __restrict__ invn) {
    __shared__ float mi[S_DIM][16];
    __shared__ float mj[S_DIM][16];
    int t = threadIdx.x;
    int i0 = blockIdx.y * 16, j0 = blockIdx.x * 16;
    for (int p = 0; p < 8; ++p) {
        int s = p * 16 + (t >> 4);
        int c = t & 15;
        mi[s][c] = mask[s * I_DIM + i0 + c];
        mj[s][c] = mask[s * I_DIM + j0 + c];
    }
    __syncthreads();
    int ii = t >> 4, jj = t & 15;
    float acc = 0.f;
#pragma unroll 8
    for (int s = 0; s < S_DIM; ++s) acc += mi[s][ii] * mj[s][jj];
    invn[(i0 + ii) * I_DIM + (j0 + jj)] = 1.0f / (acc + 0.001f);
}

// ---------------- LN + projection (bf16 MFMA), i-major for coalesced T-store ----
__global__ __launch_bounds__(256, 4) void ln_proj(const float* __restrict__ x,
                                                  const float* __restrict__ mask,
                                                  const float* __restrict__ bias,
                                                  const unsigned short* __restrict__ WpT_g,
                                                  unsigned short* __restrict__ lT,
                                                  unsigned short* __restrict__ rT) {
    __shared__ unsigned short xsh[64 * 264];
    int t = threadIdx.x;
    int w = t >> 6, lane = t & 63;
    int i = blockIdx.x >> 1;
    int s0 = (blockIdx.x & 1) * 64;

    float4 vbuf[4];
#pragma unroll
    for (int p = 0; p < 4; ++p)
        vbuf[p] = *(const float4*)(x + ((size_t)(s0 + w * 16 + p) * I_DIM + i) * IN_DIM + lane * 4);

    for (int it = 0; it < 16; ++it) {
        float4 v = vbuf[it & 3];
        if (it + 4 < 16)
            vbuf[it & 3] = *(const float4*)(x + ((size_t)(s0 + w * 16 + it + 4) * I_DIM + i) * IN_DIM + lane * 4);
        float s1 = v.x + v.y + v.z + v.w;
        float s2 = v.x * v.x + v.y * v.y + v.z * v.z + v.w * v.w;
#pragma unroll
        for (int off = 32; off >= 1; off >>= 1) {
            s1 += __shfl_xor(s1, off);
            s2 += __shfl_xor(s2, off);
        }
        float mu = s1 * (1.f / 256.f);
        float var = s2 * (1.f / 256.f) - mu * mu;
        float rs = rsqrtf(var + 1e-5f);
        unsigned int h0 = f2bf((v.x - mu) * rs);
        unsigned int h1 = f2bf((v.y - mu) * rs);
        unsigned int h2 = f2bf((v.z - mu) * rs);
        unsigned int h3 = f2bf((v.w - mu) * rs);
        uint2 pk;
        pk.x = h0 | (h1 << 16);
        pk.y = h2 | (h3 << 16);
        *(uint2*)&xsh[(w * 16 + it) * 264 + lane * 4] = pk;
    }
    __syncthreads();

    int l15 = lane & 15, q = lane >> 4;
    f32x4 acc[4];
#pragma unroll
    for (int nt = 0; nt < 4; ++nt) acc[nt] = (f32x4){0.f, 0.f, 0.f, 0.f};

    for (int k0 = 0; k0 < 256; k0 += 32) {
        bf16x8 a = *(bf16x8*)&xsh[(w * 16 + l15) * 264 + k0 + q * 8];
#pragma unroll
        for (int nt = 0; nt < 4; ++nt) {
            bf16x8 b = *(const bf16x8*)&WpT_g[(nt * 16 + l15) * 256 + k0 + q * 8];
            acc[nt] = MFMA16(a, b, acc[nt]);
        }
    }

    float mval[4];
#pragma unroll
    for (int reg = 0; reg < 4; ++reg)
        mval[reg] = mask[(size_t)(s0 + w * 16 + q * 4 + reg) * I_DIM + i];

    __syncthreads();
    unsigned short* trsh = xsh;

#pragma unroll
    for (int nt = 0; nt < 4; ++nt) {
        int f = nt * 16 + l15;
        float bv = bias[f];
        unsigned int lo = (unsigned int)f2bf((acc[nt][0] + bv) * mval[0]) |
                          ((unsigned int)f2bf((acc[nt][1] + bv) * mval[1]) << 16);
        unsigned int hi = (unsigned int)f2bf((acc[nt][2] + bv) * mval[2]) |
                          ((unsigned int)f2bf((acc[nt][3] + bv) * mval[3]) << 16);
        uint2 pk; pk.x = lo; pk.y = hi;
        *(uint2*)&trsh[f * 72 + w * 16 + q * 4] = pk;
    }
    __syncthreads();

    {
        int fr = t >> 2, so = (t & 3) * 16;
        unsigned short* dst = ((fr < 32) ? lT : rT) + ((size_t)(i * 32 + (fr & 31)) * 128 + s0 + so);
        *(uint4*)dst = *(uint4*)&trsh[fr * 72 + so];
        *(uint4*)(dst + 8) = *(uint4*)&trsh[fr * 72 + so + 8];
    }
}

// ---------------- FUSED outer + contract, 512 threads (8 waves) ----------------
// Phase 3: W2 streamed GLOBAL -> VGPR (4-deep register prefetch, fully
// unrolled loop so all indices are static). No LDS ring: removes 512 KB/block
// of LDS traffic (the R4 bandwidth wall). f-split per wave; no ph3 barriers.
__global__ __launch_bounds__(512, 4) void fused_kernel(const unsigned short* __restrict__ lT,
                                                       const unsigned short* __restrict__ rT,
                                                       const unsigned short* __restrict__ W2s,
                                                       const float* __restrict__ invn,
                                                       const float* __restrict__ out_bias,
                                                       float* __restrict__ out) {
    __shared__ unsigned short sh[32768];   // 64 KB: rT stage (34.8 KB) -> G tile (64 KB)
    char* shb = (char*)sh;
    int t = threadIdx.x;
    int w = t >> 6, lane = t & 63, l15 = lane & 15, q = lane >> 4;
    int bx = blockIdx.x;   // j-block (4 j)
    int by = blockIdx.y;   // i-block (8 i)
    int wm = w >> 1, wn = w & 1;

    // ---- stage rT tile: rows bx*128..+127 (j*32+e), cols s 0..127, pitch 136
    {
        int row = t >> 2, c0 = (t & 3) * 32;
        const unsigned short* rbase = rT + (size_t)(bx * 128 + row) * 128 + c0;
        uint4 v0 = ((const uint4*)rbase)[0];
        uint4 v1 = ((const uint4*)rbase)[1];
        uint4 v2 = ((const uint4*)rbase)[2];
        uint4 v3 = ((const uint4*)rbase)[3];
        *(uint4*)&sh[row * 136 + c0] = v0;
        *(uint4*)&sh[row * 136 + c0 + 8] = v1;
        *(uint4*)&sh[row * 136 + c0 + 16] = v2;
        *(uint4*)&sh[row * 136 + c0 + 24] = v3;
    }

    // phase-1 A fragments for k0=0, issued before the barrier (global, independent)
    const unsigned short* lbase = lT + (size_t)(by * 256 + wm * 64 + l15) * 128 + q * 8;
    bf16x8 a0_ = *(const bf16x8*)(lbase);
    bf16x8 a1_ = *(const bf16x8*)(lbase + 2048);
    bf16x8 a2_ = *(const bf16x8*)(lbase + 4096);
    bf16x8 a3_ = *(const bf16x8*)(lbase + 6144);
    __syncthreads();

    // ---- phase 1: outer GEMM, wave tile 64x64
    f32x4 acc[4][4];
#pragma unroll
    for (int mt = 0; mt < 4; ++mt)
#pragma unroll
        for (int nt = 0; nt < 4; ++nt) acc[mt][nt] = (f32x4){0.f, 0.f, 0.f, 0.f};

#pragma unroll
    for (int k0 = 0; k0 < 4; ++k0) {
        bf16x8 a[4];
        if (k0 == 0) {
            a[0] = a0_; a[1] = a1_; a[2] = a2_; a[3] = a3_;
        } else {
#pragma unroll
            for (int mt = 0; mt < 4; ++mt)
                a[mt] = *(const bf16x8*)(lbase + mt * 2048 + k0 * 32);
        }
#pragma unroll
        for (int nt = 0; nt < 4; ++nt) {
            bf16x8 b = *(bf16x8*)&sh[(wn * 64 + nt * 16 + l15) * 136 + k0 * 32 + q * 8];
#pragma unroll
            for (int mt = 0; mt < 4; ++mt)
                acc[mt][nt] = MFMA16(a[mt], b, acc[mt][nt]);
        }
    }

    // ---- W2 register prefetch (4 slices deep), launched before phase 2 so the
    // loads fly during phase-2 stores + barrier. Per-lane 16B; wave footprint =
    // 1 KB contiguous (slice-major layout) -> line-coalesced.
    const unsigned short* wlane = W2s + (w * 16 + l15) * 32 + q * 8;
    bf16x8 bpre[4];
#pragma unroll
    for (int p = 0; p < 4; ++p) bpre[p] = *(const bf16x8*)(wlane + p * 4096);

    __syncthreads();   // ph1 B-reads done before G overwrites sh

    // ---- phase 2: write G[pair][k] bf16 into LDS (swizzled)
#pragma unroll
    for (int mt = 0; mt < 4; ++mt) {
        int i_loc = wm * 2 + (mt >> 1);
        int dbase2 = ((mt & 1) * 16 + q * 4) * 2;
#pragma unroll
        for (int nt = 0; nt < 4; ++nt) {
            int pair = i_loc * 4 + wn * 2 + (nt >> 1);
            int e = (nt & 1) * 16 + l15;
            unsigned int lo = (unsigned int)f2bf(acc[mt][nt][0]) | ((unsigned int)f2bf(acc[mt][nt][1]) << 16);
            unsigned int hi = (unsigned int)f2bf(acc[mt][nt][2]) | ((unsigned int)f2bf(acc[mt][nt][3]) << 16);
            uint2 pk; pk.x = lo; pk.y = hi;
            *(uint2*)(shb + pair * 2048 + ((e * 64 + dbase2) ^ ((e & 7) << 4) ^ ((pair & 7) << 4))) = pk;
        }
    }
    __syncthreads();   // G visible to all waves

    // ---- phase 3: wave w owns f = w*16 + l15, 32 pairs, K=1024. Fully
    // unrolled; bpre indices all compile-time. Compiler manages waitcnts.
    f32x4 acc3[2];
    acc3[0] = (f32x4){0.f, 0.f, 0.f, 0.f};
    acc3[1] = (f32x4){0.f, 0.f, 0.f, 0.f};
    char* gbase0 = shb + l15 * 2048;
    char* gbase1 = shb + (16 + l15) * 2048;
    int sx = (l15 & 7) << 4;

#pragma unroll
    for (int k0 = 0; k0 < 32; ++k0) {
        bf16x8 b = bpre[k0 & 3];
        if (k0 < 28) bpre[k0 & 3] = *(const bf16x8*)(wlane + (k0 + 4) * 4096);
        int off = ((k0 * 64 + q * 16) ^ ((k0 & 7) << 4)) ^ sx;
        bf16x8 a0 = *(bf16x8*)(gbase0 + off);
        bf16x8 a1 = *(bf16x8*)(gbase1 + off);
        __builtin_amdgcn_s_setprio(1);
        acc3[0] = MFMA16(a0, b, acc3[0]);
        acc3[1] = MFMA16(a1, b, acc3[1]);
        __builtin_amdgcn_s_setprio(0);
    }

    // ---- epilogue: direct store from regs
    float bv = out_bias[w * 16 + l15];
#pragma unroll
    for (int mt3 = 0; mt3 < 2; ++mt3) {
#pragma unroll
        for (int reg = 0; reg < 4; ++reg) {
            int pair = mt3 * 16 + q * 4 + reg;
            int gi = by * 8 + (pair >> 2);
            int gj = bx * 4 + (pair & 3);
            float vinv = invn[gi * I_DIM + gj];
            out[((size_t)gi * I_DIM + gj) * 128 + w * 16 + l15] = (acc3[mt3][reg] + bv) * vinv;
        }
    }
}

extern "C" void kernel_launch(void* const* d_in, const int* in_sizes, int n_in,
                              void* d_out, int out_size, void* d_ws, size_t ws_size,
                              hipStream_t stream) {
    const float* node = (const float*)d_in[0];
    const float* mask = (const float*)d_in[1];
    const float* Wp   = (const float*)d_in[2];
    const float* bp   = (const float*)d_in[3];
    const float* W2   = (const float*)d_in[4];
    const float* bo   = (const float*)d_in[5];
    float* out = (float*)d_out;

    char* ws = (char*)d_ws;
    unsigned short* lT  = (unsigned short*)(ws);             // 3,145,728
    unsigned short* rT  = (unsigned short*)(ws + 3145728);   // 3,145,728
    unsigned short* W2s = (unsigned short*)(ws + 6291456);   // 262,144 (slice-major)
    unsigned short* WpT = (unsigned short*)(ws + 6553600);   // 32,768
    float*          inv = (float*)(ws + 6586368);            // 589,824

    hipLaunchKernelGGL(prep_cast, dim3(512), dim3(256), 0, stream, Wp, W2, WpT, W2s);
    hipLaunchKernelGGL(norm_kernel, dim3(24, 24), dim3(256), 0, stream, mask, inv);
    hipLaunchKernelGGL(ln_proj, dim3(768), dim3(256), 0, stream, node, mask, bp, WpT, lT, rT);
    hipLaunchKernelGGL(fused_kernel, dim3(96, 48), dim3(512), 0, stream,
                       lT, rT, W2s, inv, bo, out);
}